// Round 12
// baseline (171.637 us; speedup 1.0000x reference)
//
#include <hip/hip_runtime.h>
#include <math.h>

#define KK 48
#define TT 1024
#define BB 512
#define START_TAG 46
#define END_TAG 47
#define NSEG 16
#define OWN (TT / NSEG)     // 64 owned steps per segment wave
#define WARM 16             // warm-up steps for segments 1..15 (div by DEPTH)
#define DEPTH 8             // LDS staging ring depth (slots)
#define SLOTB 3072          // bytes per slot: 3 pages x 1024 (64 lanes x 16B)
#define NGRP (BB / 16)      // 32 sentence-groups of 16 (MFMA N=16)
#define NPAIR (NGRP * NSEG) // 512 (group, segment) blocks
#define WSF 50              // floats per (pair, sent) partial: 48 U + O + q0

typedef _Float16 h2 __attribute__((ext_vector_type(2)));
typedef _Float16 f16x4 __attribute__((ext_vector_type(4)));
typedef float f32x4 __attribute__((ext_vector_type(4)));

// Device-only intrinsics: __has_builtin is FALSE in the host pass.
#if defined(__HIP_DEVICE_COMPILE__)
  #if __has_builtin(__builtin_amdgcn_mfma_f32_16x16x16f16)
    #define MFMA16(A, B, C) __builtin_amdgcn_mfma_f32_16x16x16f16((A), (B), (C), 0, 0, 0)
  #elif __has_builtin(__builtin_amdgcn_mfma_f32_16x16x16_f16)
    #define MFMA16(A, B, C) __builtin_amdgcn_mfma_f32_16x16x16_f16((A), (B), (C), 0, 0, 0)
  #else
    #error "no 16x16x16 f16 mfma on this target"
  #endif
  #define SB() __builtin_amdgcn_sched_barrier(0)
  // async global->LDS DMA, 16B/lane; dest = lds base + lane*16 (linear)
  __device__ __forceinline__ void gld16(const float* g, char* l) {
      __builtin_amdgcn_global_load_lds(
          (const __attribute__((address_space(1))) void*)g,
          (__attribute__((address_space(3))) void*)l, 16, 0, 0);
  }
  #define WAITV(n) asm volatile("s_waitcnt vmcnt(" #n ")" ::: "memory")
#else
  #define MFMA16(A, B, C) (C)
  #define SB()
  __device__ __forceinline__ void gld16(const float*, char*) {}
  #define WAITV(n)
#endif

__device__ __forceinline__ h2 pkrtz(float a, float b) {
    return __builtin_bit_cast(h2, __builtin_amdgcn_cvt_pkrtz(a, b));
}

// ---------------------------------------------------------------------------
// R21: global_load_lds staging ring replaces the register prefetch ring.
//
// R19/R20 showed the compiler defeats register-ring prefetch (sinks loads;
// VGPR=76 < ring size) and sched_barrier pinning only recovered ~10 us (seg
// ~50 us ~= 1500 cyc/step vs ~450 compute+ds chain). R21 stages feats via
// __builtin_amdgcn_global_load_lds (side-effecting: cannot be sunk; zero
// VGPR cost): DEPTH=8 ring x 3KB slots in LDS, counted s_waitcnt vmcnt(21)
// per step (7 slots x 3 loads stay in flight - never drain to 0, T4 rule),
// then 3x conflict-free ds_read_b128 (lane l reads its own 16B: sentence
// l&15, floats 16c+4*(l>>4) - per-lane values BIT-IDENTICAL to the register
// version, numerics unchanged). Re-issue the slot's 3 DMA loads for t+DEPTH
// right after ef consumes the reads (lgkmcnt drained by dataflow => no
// WAR on the slot). MFMA datapath/ledger/stitching untouched from R18-R20.
// Predicted: seg 15-30 us (LDS_Block_Size=24576 confirms deployment),
// bench 125-150, absmax 32. Falsifier: seg ~50 us with ring in place =>
// gather is demand-limited at L3/DRAM => pre-transpose feats next.
// ---------------------------------------------------------------------------

template <bool EXACT>
__device__ __forceinline__ void run_seg(const float* __restrict__ fbl,
                                        const float* __restrict__ trans,
                                        char* ldsb,
                                        int lane, int g4, int r0, int nsteps,
                                        float (&wv)[3][4], int& esumO, int& eswmO,
                                        float& q0O) {
    // A-frags (constant): A[m][c] holds E rows 16m+(lane&15), k 16c+4*g4+j
    f16x4 Af[3][3];
    #pragma unroll
    for (int m = 0; m < 3; ++m) {
        const int row = 16 * m + (lane & 15);
        #pragma unroll
        for (int c = 0; c < 3; ++c) {
            #pragma unroll
            for (int j = 0; j < 4; ++j)
                Af[m][c][j] = (_Float16)__expf(trans[row * KK + 16 * c + 4 * g4 + j]);
        }
    }

    // B-frags (state): alpha[k = 16c + 4*g4 + j][sent = lane&15], f16
    f16x4 bf[3];
    if (EXACT) {
        #pragma unroll
        for (int c = 0; c < 3; ++c) bf[c] = (f16x4)(_Float16)0.0f;
        if (g4 == 3) bf[2][2] = (_Float16)1.0f;   // k = 32+4*3+2 = 46 = START
    } else {
        #pragma unroll
        for (int c = 0; c < 3; ++c) bf[c] = (f16x4)(_Float16)1.0f;  // all-ones
    }

    int esum = 0, eswm = 0;
    float q0v = 1.0f;

    // ---- prologue: drain prior VMEM (deterministic vmcnt), fill the ring ----
    WAITV(0);
    SB();
    #pragma unroll
    for (int j = 0; j < DEPTH; ++j) {
        int t = r0 + j; if (t > TT - 1) t = TT - 1;
        char* slot = ldsb + j * SLOTB;
        #pragma unroll
        for (int c = 0; c < 3; ++c)
            gld16(fbl + (size_t)t * KK + 16 * c + 4 * g4, slot + c * 1024);
    }

    for (int s0 = 0; s0 < nsteps; s0 += DEPTH) {
        #pragma unroll
        for (int j = 0; j < DEPTH; ++j) {
            const int st = s0 + j;
            char* slot = ldsb + j * SLOTB;
            // slot j's 3 loads are the oldest of 24 outstanding: wait to 21
            WAITV(21);
            SB();
            f32x4 ftc[3];
            #pragma unroll
            for (int c = 0; c < 3; ++c)
                ftc[c] = *(const f32x4*)(slot + c * 1024 + lane * 16);
            // ef consumes the reads (forces lgkmcnt drain before reissue)
            float ef[3][4];
            #pragma unroll
            for (int m = 0; m < 3; ++m)
                #pragma unroll
                for (int r = 0; r < 4; ++r) ef[m][r] = __expf(ftc[m][r]);
            // re-issue slot j for step st+DEPTH (WAR-safe: reads consumed)
            SB();
            {
                int tn = r0 + st + DEPTH; if (tn > TT - 1) tn = TT - 1;
                #pragma unroll
                for (int c = 0; c < 3; ++c)
                    gld16(fbl + (size_t)tn * KK + 16 * c + 4 * g4, slot + c * 1024);
            }
            // D = E * Alpha : 3 output tiles x 3 K-chunks
            const f32x4 z = {0.f, 0.f, 0.f, 0.f};
            f32x4 a0 = MFMA16(Af[0][0], bf[0], z);
            f32x4 a1 = MFMA16(Af[1][0], bf[0], z);
            f32x4 a2 = MFMA16(Af[2][0], bf[0], z);
            a0 = MFMA16(Af[0][1], bf[1], a0);
            a1 = MFMA16(Af[1][1], bf[1], a1);
            a2 = MFMA16(Af[2][1], bf[1], a2);
            a0 = MFMA16(Af[0][2], bf[2], a0);
            a1 = MFMA16(Af[1][2], bf[2], a1);
            a2 = MFMA16(Af[2][2], bf[2], a2);
            // alpha_raw = D .* ef
            #pragma unroll
            for (int r = 0; r < 4; ++r) {
                wv[0][r] = a0[r] * ef[0][r];
                wv[1][r] = a1[r] * ef[1][r];
                wv[2][r] = a2[r] * ef[2][r];
            }
            // per-sentence pow-2 norm: ref = row-0 raw value of own column
            float ref = __shfl(wv[0][0], lane & 15, 64);
            int eb = ((__float_as_int(ref) >> 23) & 0xff) - 127;
            esum += eb;
            float sc = __int_as_float((127 - eb) << 23);
            #pragma unroll
            for (int m = 0; m < 3; ++m)
                #pragma unroll
                for (int r = 0; r < 4; ++r) wv[m][r] *= sc;
            if (!EXACT && st == WARM - 1) { eswm = esum; q0v = ref * sc; }
            // pack scaled alpha -> next B-frags (D-layout == B-layout)
            #pragma unroll
            for (int m = 0; m < 3; ++m) {
                h2 lo = pkrtz(wv[m][0], wv[m][1]);
                h2 hi = pkrtz(wv[m][2], wv[m][3]);
                bf[m][0] = lo.x; bf[m][1] = lo.y; bf[m][2] = hi.x; bf[m][3] = hi.y;
            }
        }
    }
    esumO = esum; eswmO = eswm; q0O = q0v;
}

__global__ __launch_bounds__(64)
void crf_seg_kernel(const float* __restrict__ feats,
                    const float* __restrict__ trans,
                    float* __restrict__ ws) {
    const int pair = blockIdx.x;        // g*16 + seg
    const int g = pair >> 4;
    const int seg = pair & 15;
    const int lane = threadIdx.x & 63;
    const int g4 = lane >> 4;
    const float* fbl = feats + (size_t)(g * 16 + (lane & 15)) * TT * KK;

    __shared__ __align__(16) char ldsb[DEPTH * SLOTB];   // 24 KB ring

    float wv[3][4];
    int esum, eswm; float q0v;
    if (seg == 0) run_seg<true >(fbl, trans, ldsb, lane, g4, 0, OWN,
                                 wv, esum, eswm, q0v);
    else          run_seg<false>(fbl, trans, ldsb, lane, g4, seg * OWN - WARM,
                                 OWN + WARM, wv, esum, eswm, q0v);

    // partials: ws[(pair*16 + sent)*WSF + {0..47: U, 48: O, 49: q0}]
    float* base = ws + ((size_t)pair * 16 + (lane & 15)) * WSF;
    #pragma unroll
    for (int m = 0; m < 3; ++m)
        #pragma unroll
        for (int r = 0; r < 4; ++r)
            base[16 * m + 4 * g4 + r] = wv[m][r];
    if (lane < 16) {
        float* b2 = ws + ((size_t)pair * 16 + lane) * WSF;
        b2[48] = (float)(esum - eswm);   // exact: |O| << 2^24
        b2[49] = q0v;
    }
}

__global__ __launch_bounds__(256)
void crf_combine(const float* __restrict__ feats,
                 const float* __restrict__ trans,
                 const int* __restrict__ tags,
                 const float* __restrict__ ws,
                 float* __restrict__ out) {
    const int s = blockIdx.x;           // sentence
    const int g = s >> 4;
    const int sidx = s & 15;
    const int tid = threadIdx.x;
    const int lane = tid & 63;
    const int w = tid >> 6;
    const int* tg = tags + (size_t)s * TT;
    const float* fbs = feats + (size_t)s * TT * KK;

    __shared__ float red[4];

    // gold score: 1024 t's over 256 threads (4 waves), LDS reduce
    float gacc = 0.0f;
    #pragma unroll
    for (int it = 0; it < TT / 256; ++it) {
        int t = tid + it * 256;
        int cur = tg[t];
        int prev = (t == 0) ? START_TAG : tg[t - 1];
        gacc += trans[cur * KK + prev] + fbs[(size_t)t * KK + cur];
    }
    #pragma unroll
    for (int off = 32; off; off >>= 1) gacc += __shfl_xor(gacc, off, 64);
    if (lane == 0) red[w] = gacc;
    __syncthreads();

    if (w == 0) {
        // Z tail: sum_i exp(trans[END][i]) * U_last[i]
        float val = 0.0f;
        if (lane < KK)
            val = __expf(trans[END_TAG * KK + lane]) *
                  ws[(((size_t)g * 16 + 15) * 16 + sidx) * WSF + lane];
        #pragma unroll
        for (int off = 32; off; off >>= 1) val += __shfl_xor(val, off, 64);

        // ledgers + scalar stitches (lane-parallel over segments)
        float stv = 0.0f;
        if (lane >= 1 && lane < NSEG) {
            float Uprev0 = ws[(((size_t)g * 16 + lane - 1) * 16 + sidx) * WSF + 0];
            float q0w    = ws[(((size_t)g * 16 + lane) * 16 + sidx) * WSF + 49];
            stv = __logf(Uprev0) - __logf(q0w);
        }
        if (lane < NSEG)
            stv += ws[(((size_t)g * 16 + lane) * 16 + sidx) * WSF + 48] *
                   0.6931471805599453f;
        #pragma unroll
        for (int off = 32; off; off >>= 1) stv += __shfl_xor(stv, off, 64);

        if (lane == 0) {
            float gold = red[0] + red[1] + red[2] + red[3] +
                         trans[END_TAG * KK + tg[TT - 1]];
            out[s] = __logf(val) + stv - gold;
        }
    }
}

extern "C" void kernel_launch(void* const* d_in, const int* in_sizes, int n_in,
                              void* d_out, int out_size, void* d_ws, size_t ws_size,
                              hipStream_t stream) {
    const float* feats = (const float*)d_in[0];
    const float* trans = (const float*)d_in[1];
    const int* tags = (const int*)d_in[2];
    float* out = (float*)d_out;
    float* ws = (float*)d_ws;           // needs NPAIR*16*WSF*4 = 1.64 MB

    crf_seg_kernel<<<NPAIR, 64, 0, stream>>>(feats, trans, ws);
    crf_combine<<<BB, 256, 0, stream>>>(feats, trans, tags, ws, out);
}

// Round 13
// 168.614 us; speedup vs baseline: 1.0179x; 1.0179x over previous
//
#include <hip/hip_runtime.h>
#include <math.h>

#define KK 48
#define TT 1024
#define BB 512
#define START_TAG 46
#define END_TAG 47
#define NSEG 16
#define OWN (TT / NSEG)     // 64 owned steps per segment wave
#define WARM 16             // warm-up steps for segments 1..15 (div by CH)
#define CH 8                // steps per staged chunk
#define SSTRIDE 1584        // padded bytes/sentence/chunk (8*192 + 48 pad)
#define NINST 25            // DMA instructions per chunk (ceil(16*1584/1024))
#define CHB (NINST * 1024)  // 25600 B per chunk buffer
#define NGRP (BB / 16)      // 32 sentence-groups of 16 (MFMA N=16)
#define NPAIR (NGRP * NSEG) // 512 (group, segment) blocks
#define WSF 50              // floats per (pair, sent) partial: 48 U + O + q0

typedef _Float16 h2 __attribute__((ext_vector_type(2)));
typedef _Float16 f16x4 __attribute__((ext_vector_type(4)));
typedef float f32x4 __attribute__((ext_vector_type(4)));

// Device-only intrinsics: __has_builtin is FALSE in the host pass.
#if defined(__HIP_DEVICE_COMPILE__)
  #if __has_builtin(__builtin_amdgcn_mfma_f32_16x16x16f16)
    #define MFMA16(A, B, C) __builtin_amdgcn_mfma_f32_16x16x16f16((A), (B), (C), 0, 0, 0)
  #elif __has_builtin(__builtin_amdgcn_mfma_f32_16x16x16_f16)
    #define MFMA16(A, B, C) __builtin_amdgcn_mfma_f32_16x16x16_f16((A), (B), (C), 0, 0, 0)
  #else
    #error "no 16x16x16 f16 mfma on this target"
  #endif
  #define SB() __builtin_amdgcn_sched_barrier(0)
  __device__ __forceinline__ void gld16(const float* g, char* l) {
      __builtin_amdgcn_global_load_lds(
          (const __attribute__((address_space(1))) void*)g,
          (__attribute__((address_space(3))) void*)l, 16, 0, 0);
  }
  #define WAITV(n) asm volatile("s_waitcnt vmcnt(" #n ")" ::: "memory")
  #define WAITL()  asm volatile("s_waitcnt lgkmcnt(0)" ::: "memory")
#else
  #define MFMA16(A, B, C) (C)
  #define SB()
  __device__ __forceinline__ void gld16(const float*, char*) {}
  #define WAITV(n)
  #define WAITL()
#endif

__device__ __forceinline__ h2 pkrtz(float a, float b) {
    return __builtin_bit_cast(h2, __builtin_amdgcn_cvt_pkrtz(a, b));
}

// ---------------------------------------------------------------------------
// R22: chunked-burst DMA staging (8 steps per wait, contiguous 1KB bursts).
//
// R19-R21 post-mortems: register-ring prefetch is sunk by the compiler
// (R19/R20), and R21's per-step slot DMA still drained per step (compiler
// inserts conservative vmcnt before each dependent ds_read; consumption
// granularity = 1 step => 1 drain/step). Plus every load instruction
// gathered 16 x 64B from addresses equal mod 2^16 (sentence stride 3*2^16)
// => same-channel DRAM serialization. R22 stages CH=8 steps per chunk,
// SENTENCE-MAJOR: 25 DMA instructions whose 64 lanes cover contiguous 1KB
// of one sentence (lane->(q,rem) via magic-div by 99 in 16B units; sentence
// stride padded to 1584B for LDS banking). Double-buffered, one vmcnt(25)
// per 8 steps; unconditional clamped tail refills keep outstanding = 50
// before each wait (exact ledger). Consume: 3x ds_read_b128/lane/step at
// s*1584 + st2*192 + 64c + 16*q4 — verified to round-trip to the exact
// float indices of the old direct loads => BIT-IDENTICAL numerics.
// MFMA datapath / norm ledger / stitching untouched (R18-proven).
// Predicted: seg 50 -> 15-25 us (LDS_Block_Size=51200 confirms deploy),
// seg hbm ~3000+, bench 130-142, absmax exactly 32.
// ---------------------------------------------------------------------------

__device__ __forceinline__ void stage_chunk(const float* __restrict__ gbase,
                                            char* buf, const int (&off)[NINST],
                                            int br) {
    const int rowoff = br * KK;
    #pragma unroll
    for (int i = 0; i < NINST; ++i)
        gld16(gbase + off[i] + rowoff, buf + i * 1024);
}

template <bool EXACT>
__device__ __forceinline__ void run_seg(const float* __restrict__ gbase,
                                        const float* __restrict__ trans,
                                        char* lds,
                                        int lane, int r0, int nsteps,
                                        float (&wv)[3][4], int& esumO, int& eswmO,
                                        float& q0O) {
    const int s = lane & 15;        // sentence within group (MFMA column)
    const int g4 = lane >> 4;       // row-quad group within fragments

    // per-lane chunk-invariant DMA source offsets (float index), validity folded
    int off[NINST];
    #pragma unroll
    for (int i = 0; i < NINST; ++i) {
        int u = i * 64 + lane;              // 16B-unit flat position
        int q = (u * 663) >> 16;            // u / 99 (exact for u < 64297)
        int rem16 = u - q * 99;
        bool valid = (q < 16) & (rem16 < 96);
        off[i] = valid ? (q * (TT * KK) + rem16 * 4) : 0;
    }

    // A-frags (constant): A[m][c] holds E rows 16m+s, k 16c+4*g4+j
    f16x4 Af[3][3];
    #pragma unroll
    for (int m = 0; m < 3; ++m) {
        const int row = 16 * m + s;
        #pragma unroll
        for (int c = 0; c < 3; ++c) {
            #pragma unroll
            for (int j = 0; j < 4; ++j)
                Af[m][c][j] = (_Float16)__expf(trans[row * KK + 16 * c + 4 * g4 + j]);
        }
    }

    // B-frags (state): alpha[k = 16c + 4*g4 + j][sent = s], f16
    f16x4 bf[3];
    if (EXACT) {
        #pragma unroll
        for (int c = 0; c < 3; ++c) bf[c] = (f16x4)(_Float16)0.0f;
        if (g4 == 3) bf[2][2] = (_Float16)1.0f;   // k = 32+4*3+2 = 46 = START
    } else {
        #pragma unroll
        for (int c = 0; c < 3; ++c) bf[c] = (f16x4)(_Float16)1.0f;  // all-ones
    }

    int esum = 0, eswm = 0;
    float q0v = 1.0f;

    const int nch = nsteps / CH;
    // prologue: fill both buffers (50 loads outstanding)
    stage_chunk(gbase, lds, off, r0);
    stage_chunk(gbase, lds + CHB, off, r0 + CH);

    for (int ch = 0; ch < nch; ++ch) {
        char* buf = lds + (ch & 1) * CHB;
        WAITV(25);          // oldest 25 (this chunk's) landed; 25 stay in flight
        SB();
        #pragma unroll
        for (int st2 = 0; st2 < CH; ++st2) {
            const int st = ch * CH + st2;
            const char* p = buf + s * SSTRIDE + st2 * 192 + g4 * 16;
            f32x4 ftc[3];
            #pragma unroll
            for (int c = 0; c < 3; ++c)
                ftc[c] = *(const f32x4*)(p + c * 64);
            float ef[3][4];
            #pragma unroll
            for (int m = 0; m < 3; ++m)
                #pragma unroll
                for (int r = 0; r < 4; ++r) ef[m][r] = __expf(ftc[m][r]);
            // D = E * Alpha : 3 output tiles x 3 K-chunks
            const f32x4 z = {0.f, 0.f, 0.f, 0.f};
            f32x4 a0 = MFMA16(Af[0][0], bf[0], z);
            f32x4 a1 = MFMA16(Af[1][0], bf[0], z);
            f32x4 a2 = MFMA16(Af[2][0], bf[0], z);
            a0 = MFMA16(Af[0][1], bf[1], a0);
            a1 = MFMA16(Af[1][1], bf[1], a1);
            a2 = MFMA16(Af[2][1], bf[1], a2);
            a0 = MFMA16(Af[0][2], bf[2], a0);
            a1 = MFMA16(Af[1][2], bf[2], a1);
            a2 = MFMA16(Af[2][2], bf[2], a2);
            // alpha_raw = D .* ef
            #pragma unroll
            for (int r = 0; r < 4; ++r) {
                wv[0][r] = a0[r] * ef[0][r];
                wv[1][r] = a1[r] * ef[1][r];
                wv[2][r] = a2[r] * ef[2][r];
            }
            // per-sentence pow-2 norm: ref = row-0 raw value of own column
            float ref = __shfl(wv[0][0], s, 64);
            int eb = ((__float_as_int(ref) >> 23) & 0xff) - 127;
            esum += eb;
            float sc = __int_as_float((127 - eb) << 23);
            #pragma unroll
            for (int m = 0; m < 3; ++m)
                #pragma unroll
                for (int r = 0; r < 4; ++r) wv[m][r] *= sc;
            if (!EXACT && st == WARM - 1) { eswm = esum; q0v = ref * sc; }
            // pack scaled alpha -> next B-frags (D-layout == B-layout)
            #pragma unroll
            for (int m = 0; m < 3; ++m) {
                h2 lo = pkrtz(wv[m][0], wv[m][1]);
                h2 hi = pkrtz(wv[m][2], wv[m][3]);
                bf[m][0] = lo.x; bf[m][1] = lo.y; bf[m][2] = hi.x; bf[m][3] = hi.y;
            }
        }
        WAITL();            // ds_reads of this buffer fully drained
        // unconditional refill (clamped rows past end) keeps ledger exact:
        // outstanding is always 50 before each WAITV(25)
        int brn = r0 + (ch + 2) * CH;
        if (brn > TT - CH) brn = TT - CH;
        stage_chunk(gbase, buf, off, brn);
    }
    esumO = esum; eswmO = eswm; q0O = q0v;
}

__global__ __launch_bounds__(64)
void crf_seg_kernel(const float* __restrict__ feats,
                    const float* __restrict__ trans,
                    float* __restrict__ ws) {
    const int pair = blockIdx.x;        // g*16 + seg
    const int g = pair >> 4;
    const int seg = pair & 15;
    const int lane = threadIdx.x & 63;
    const int g4 = lane >> 4;
    const float* gbase = feats + (size_t)g * 16 * TT * KK;

    __shared__ __align__(16) char lds[2 * CHB];   // 50 KB double buffer

    float wv[3][4];
    int esum, eswm; float q0v;
    if (seg == 0) run_seg<true >(gbase, trans, lds, lane, 0, OWN,
                                 wv, esum, eswm, q0v);
    else          run_seg<false>(gbase, trans, lds, lane, seg * OWN - WARM,
                                 OWN + WARM, wv, esum, eswm, q0v);

    // partials: ws[(pair*16 + sent)*WSF + {0..47: U, 48: O, 49: q0}]
    float* base = ws + ((size_t)pair * 16 + (lane & 15)) * WSF;
    #pragma unroll
    for (int m = 0; m < 3; ++m)
        #pragma unroll
        for (int r = 0; r < 4; ++r)
            base[16 * m + 4 * g4 + r] = wv[m][r];
    if (lane < 16) {
        float* b2 = ws + ((size_t)pair * 16 + lane) * WSF;
        b2[48] = (float)(esum - eswm);   // exact: |O| << 2^24
        b2[49] = q0v;
    }
}

__global__ __launch_bounds__(256)
void crf_combine(const float* __restrict__ feats,
                 const float* __restrict__ trans,
                 const int* __restrict__ tags,
                 const float* __restrict__ ws,
                 float* __restrict__ out) {
    const int s = blockIdx.x;           // sentence
    const int g = s >> 4;
    const int sidx = s & 15;
    const int tid = threadIdx.x;
    const int lane = tid & 63;
    const int w = tid >> 6;
    const int* tg = tags + (size_t)s * TT;
    const float* fbs = feats + (size_t)s * TT * KK;

    __shared__ float red[4];

    // gold score: 1024 t's over 256 threads (4 waves), LDS reduce
    float gacc = 0.0f;
    #pragma unroll
    for (int it = 0; it < TT / 256; ++it) {
        int t = tid + it * 256;
        int cur = tg[t];
        int prev = (t == 0) ? START_TAG : tg[t - 1];
        gacc += trans[cur * KK + prev] + fbs[(size_t)t * KK + cur];
    }
    #pragma unroll
    for (int off = 32; off; off >>= 1) gacc += __shfl_xor(gacc, off, 64);
    if (lane == 0) red[w] = gacc;
    __syncthreads();

    if (w == 0) {
        // Z tail: sum_i exp(trans[END][i]) * U_last[i]
        float val = 0.0f;
        if (lane < KK)
            val = __expf(trans[END_TAG * KK + lane]) *
                  ws[(((size_t)g * 16 + 15) * 16 + sidx) * WSF + lane];
        #pragma unroll
        for (int off = 32; off; off >>= 1) val += __shfl_xor(val, off, 64);

        // ledgers + scalar stitches (lane-parallel over segments)
        float stv = 0.0f;
        if (lane >= 1 && lane < NSEG) {
            float Uprev0 = ws[(((size_t)g * 16 + lane - 1) * 16 + sidx) * WSF + 0];
            float q0w    = ws[(((size_t)g * 16 + lane) * 16 + sidx) * WSF + 49];
            stv = __logf(Uprev0) - __logf(q0w);
        }
        if (lane < NSEG)
            stv += ws[(((size_t)g * 16 + lane) * 16 + sidx) * WSF + 48] *
                   0.6931471805599453f;
        #pragma unroll
        for (int off = 32; off; off >>= 1) stv += __shfl_xor(stv, off, 64);

        if (lane == 0) {
            float gold = red[0] + red[1] + red[2] + red[3] +
                         trans[END_TAG * KK + tg[TT - 1]];
            out[s] = __logf(val) + stv - gold;
        }
    }
}

extern "C" void kernel_launch(void* const* d_in, const int* in_sizes, int n_in,
                              void* d_out, int out_size, void* d_ws, size_t ws_size,
                              hipStream_t stream) {
    const float* feats = (const float*)d_in[0];
    const float* trans = (const float*)d_in[1];
    const int* tags = (const int*)d_in[2];
    float* out = (float*)d_out;
    float* ws = (float*)d_ws;           // needs NPAIR*16*WSF*4 = 1.64 MB

    crf_seg_kernel<<<NPAIR, 64, 0, stream>>>(feats, trans, ws);
    crf_combine<<<BB, 256, 0, stream>>>(feats, trans, tags, ws, out);
}

// Round 15
// 167.846 us; speedup vs baseline: 1.0226x; 1.0046x over previous
//
#include <hip/hip_runtime.h>
#include <math.h>

#define KK 48
#define TT 1024
#define BB 512
#define START_TAG 46
#define END_TAG 47
#define NSEG 16
#define OWN (TT / NSEG)     // 64 owned steps per segment wave
#define WARM 16             // warm-up steps for segments 1..15 (div by CH)
#define CH 8                // steps per staged chunk
#define SSTRIDE 1584        // padded bytes/sentence/chunk (8*192 + 48 pad)
#define NINST 25            // DMA instructions per chunk (ceil(16*1584/1024))
#define CHB (NINST * 1024)  // 25600 B per chunk buffer
#define NGRP (BB / 16)      // 32 sentence-groups of 16 (MFMA N=16)
#define NPAIR (NGRP * NSEG) // 512 (group, segment) blocks
#define WSF 50              // floats per (pair, sent) partial: 48 U + O + q0

typedef _Float16 h2 __attribute__((ext_vector_type(2)));
typedef _Float16 f16x4 __attribute__((ext_vector_type(4)));
typedef float f32x4 __attribute__((ext_vector_type(4)));
typedef int i2 __attribute__((ext_vector_type(2)));

// Device-only intrinsics: __has_builtin is FALSE in the host pass.
#if defined(__HIP_DEVICE_COMPILE__)
  #if __has_builtin(__builtin_amdgcn_mfma_f32_16x16x16f16)
    #define MFMA16(A, B, C) __builtin_amdgcn_mfma_f32_16x16x16f16((A), (B), (C), 0, 0, 0)
  #elif __has_builtin(__builtin_amdgcn_mfma_f32_16x16x16_f16)
    #define MFMA16(A, B, C) __builtin_amdgcn_mfma_f32_16x16x16_f16((A), (B), (C), 0, 0, 0)
  #else
    #error "no 16x16x16 f16 mfma on this target"
  #endif
  #define SB() __builtin_amdgcn_sched_barrier(0)
  __device__ __forceinline__ void gld16(const float* g, char* l) {
      __builtin_amdgcn_global_load_lds(
          (const __attribute__((address_space(1))) void*)g,
          (__attribute__((address_space(3))) void*)l, 16, 0, 0);
  }
  #define WAITV(n) asm volatile("s_waitcnt vmcnt(" #n ")" ::: "memory")
  #define WAITL()  asm volatile("s_waitcnt lgkmcnt(0)" ::: "memory")
#else
  #define MFMA16(A, B, C) (C)
  #define SB()
  __device__ __forceinline__ void gld16(const float*, char*) {}
  #define WAITV(n)
  #define WAITL()
#endif

__device__ __forceinline__ h2 pkrtz(float a, float b) {
    return __builtin_bit_cast(h2, __builtin_amdgcn_cvt_pkrtz(a, b));
}

// ---------------------------------------------------------------------------
// R24 (= R23 resubmitted; round 14 was an infra failure, no data).
// Predictive pow-2 scaling — the cross-lane op leaves the critical path.
//
// R20/R21/R22: three totally different memory schemes, identical ~50us seg
// (1500 cyc/step) => memory-pattern hypothesis FALSIFIED; at 0.5 waves/SIMD
// the per-step serial chain is fully exposed (R19 PMC: VALU issue ~323,
// matrix pipe ~126, rest = dependency stalls; worst link = MFMA -> wv ->
// shfl(bpermute ~60-100) -> scale -> pack -> bf).
// R24 (staging/bytes/grid IDENTICAL to R22, single-variable A/B): the ledger
// only needs the APPLIED exponent to be exactly accumulated - not that it be
// derived from this step's output. Scale predictively:
//   s_t = ehat_t + C0 + d_{t-1}
// ehat_t = floor(log2 e^{feat_t[row0]}) (read early from LDS, off-chain),
// C0 = 6 ~ log2(row-sum of E), d_{t-1} = residual exponent from LAST step's
// shfl (one step of slack => bpermute latency hidden). Exactly damped:
// d_t = (C_t - C0) + (e_t - ehat_t), no accumulation, |d| <~ 6 (f16-safe).
// esum += s_t (exact int). Chain: bf -> 9 MFMA -> 12 mul(ef*sc precomp) ->
// 6 cvt_pkrtz -> dword-pair bit_cast into bf (no sub-reg inserts).
// Numerics: ledger exact; f16 rounding points shift => absmax may move off
// exactly-32 (expect 20-50, threshold 90.24).
// Predicted: chain-hypothesis true => seg 50 -> 28-38us, bench 146-157.
// Flat => congestion proven => pivot to occupancy (NSEG=64) next.
// ---------------------------------------------------------------------------

__device__ __forceinline__ void stage_chunk(const float* __restrict__ gbase,
                                            char* buf, const int (&off)[NINST],
                                            int br) {
    const int rowoff = br * KK;
    #pragma unroll
    for (int i = 0; i < NINST; ++i)
        gld16(gbase + off[i] + rowoff, buf + i * 1024);
}

template <bool EXACT>
__device__ __forceinline__ void run_seg(const float* __restrict__ gbase,
                                        const float* __restrict__ trans,
                                        char* lds,
                                        int lane, int r0, int nsteps,
                                        float (&wv)[3][4], int& esumO, int& eswmO,
                                        float& q0O) {
    const int s = lane & 15;        // sentence within group (MFMA column)
    const int g4 = lane >> 4;       // row-quad group within fragments

    // per-lane chunk-invariant DMA source offsets (float index), validity folded
    int off[NINST];
    #pragma unroll
    for (int i = 0; i < NINST; ++i) {
        int u = i * 64 + lane;              // 16B-unit flat position
        int q = (u * 663) >> 16;            // u / 99 (exact for u < 64297)
        int rem16 = u - q * 99;
        bool valid = (q < 16) & (rem16 < 96);
        off[i] = valid ? (q * (TT * KK) + rem16 * 4) : 0;
    }

    // A-frags (constant): A[m][c] holds E rows 16m+s, k 16c+4*g4+j
    f16x4 Af[3][3];
    #pragma unroll
    for (int m = 0; m < 3; ++m) {
        const int row = 16 * m + s;
        #pragma unroll
        for (int c = 0; c < 3; ++c) {
            #pragma unroll
            for (int j = 0; j < 4; ++j)
                Af[m][c][j] = (_Float16)__expf(trans[row * KK + 16 * c + 4 * g4 + j]);
        }
    }

    // B-frags (state): alpha[k = 16c + 4*g4 + j][sent = s], f16
    f16x4 bf[3];
    if (EXACT) {
        #pragma unroll
        for (int c = 0; c < 3; ++c) bf[c] = (f16x4)(_Float16)0.0f;
        if (g4 == 3) bf[2][2] = (_Float16)1.0f;   // k = 32+4*3+2 = 46 = START
    } else {
        #pragma unroll
        for (int c = 0; c < 3; ++c) bf[c] = (f16x4)(_Float16)1.0f;  // all-ones
    }

    int esum = 0, eswm = 0;
    float q0v = 1.0f;
    int refSb = 0x3F800000;   // last step's scaled row-0 value (bits); init 1.0f

    const int nch = nsteps / CH;
    // prologue: fill both buffers (50 loads outstanding)
    stage_chunk(gbase, lds, off, r0);
    stage_chunk(gbase, lds + CHB, off, r0 + CH);

    for (int ch = 0; ch < nch; ++ch) {
        char* buf = lds + (ch & 1) * CHB;
        WAITV(25);          // oldest 25 (this chunk's) landed; 25 stay in flight
        SB();
        #pragma unroll
        for (int st2 = 0; st2 < CH; ++st2) {
            const int st = ch * CH + st2;
            const char* p = buf + s * SSTRIDE + st2 * 192 + g4 * 16;
            // row-0 feature of own sentence (uniform across the column's 4 lanes)
            float f0 = *(const float*)(buf + s * SSTRIDE + st2 * 192);
            f32x4 ftc[3];
            #pragma unroll
            for (int c = 0; c < 3; ++c)
                ftc[c] = *(const f32x4*)(p + c * 64);

            // warm-boundary snapshot: refSb is step WARM-1's scaled row0;
            // esum here = sum of s_0..s_{WARM-1} (before this step's add)
            if (!EXACT && st == WARM) { eswm = esum; q0v = __int_as_float(refSb); }

            // predictive per-column pow-2 scale (exact int ledger)
            int dprev = ((refSb >> 23) & 0xff) - 127;
            int ehat = (int)floorf(f0 * 1.44269504f);
            int sT = ehat + 6 + dprev;
            esum += sT;
            float sc = __int_as_float((127 - sT) << 23);
            // efs = exp(feat) * sc, fully off the bf chain
            float efs[3][4];
            #pragma unroll
            for (int m = 0; m < 3; ++m)
                #pragma unroll
                for (int r = 0; r < 4; ++r) efs[m][r] = __expf(ftc[m][r]) * sc;

            // D = E * Alpha : 3 output tiles x 3 K-chunks (C-chained)
            const f32x4 z = {0.f, 0.f, 0.f, 0.f};
            f32x4 a0 = MFMA16(Af[0][0], bf[0], z);
            f32x4 a1 = MFMA16(Af[1][0], bf[0], z);
            f32x4 a2 = MFMA16(Af[2][0], bf[0], z);
            a0 = MFMA16(Af[0][1], bf[1], a0);
            a1 = MFMA16(Af[1][1], bf[1], a1);
            a2 = MFMA16(Af[2][1], bf[1], a2);
            a0 = MFMA16(Af[0][2], bf[2], a0);
            a1 = MFMA16(Af[1][2], bf[2], a1);
            a2 = MFMA16(Af[2][2], bf[2], a2);

            // wv = D .* efs (single on-chain mul layer; already scaled)
            #pragma unroll
            for (int r = 0; r < 4; ++r) {
                wv[0][r] = a0[r] * efs[0][r];
                wv[1][r] = a1[r] * efs[1][r];
                wv[2][r] = a2[r] * efs[2][r];
            }
            // pack -> next B-frags via dword pairs (no sub-register inserts)
            #pragma unroll
            for (int m = 0; m < 3; ++m) {
                i2 pk;
                pk.x = __builtin_bit_cast(int, pkrtz(wv[m][0], wv[m][1]));
                pk.y = __builtin_bit_cast(int, pkrtz(wv[m][2], wv[m][3]));
                bf[m] = __builtin_bit_cast(f16x4, pk);
            }
            // issue the residual broadcast; consumed NEXT step (latency hidden)
            refSb = __shfl(__float_as_int(wv[0][0]), s, 64);
        }
        WAITL();            // ds_reads of this buffer fully drained
        // unconditional refill (clamped) keeps ledger exact: 50 before each wait
        int brn = r0 + (ch + 2) * CH;
        if (brn > TT - CH) brn = TT - CH;
        stage_chunk(gbase, buf, off, brn);
    }
    esumO = esum; eswmO = eswm; q0O = q0v;
}

__global__ __launch_bounds__(64)
void crf_seg_kernel(const float* __restrict__ feats,
                    const float* __restrict__ trans,
                    float* __restrict__ ws) {
    const int pair = blockIdx.x;        // g*16 + seg
    const int g = pair >> 4;
    const int seg = pair & 15;
    const int lane = threadIdx.x & 63;
    const int g4 = lane >> 4;
    const float* gbase = feats + (size_t)g * 16 * TT * KK;

    __shared__ __align__(16) char lds[2 * CHB];   // 50 KB double buffer

    float wv[3][4];
    int esum, eswm; float q0v;
    if (seg == 0) run_seg<true >(gbase, trans, lds, lane, 0, OWN,
                                 wv, esum, eswm, q0v);
    else          run_seg<false>(gbase, trans, lds, lane, seg * OWN - WARM,
                                 OWN + WARM, wv, esum, eswm, q0v);

    // partials: ws[(pair*16 + sent)*WSF + {0..47: U, 48: O, 49: q0}]
    float* base = ws + ((size_t)pair * 16 + (lane & 15)) * WSF;
    #pragma unroll
    for (int m = 0; m < 3; ++m)
        #pragma unroll
        for (int r = 0; r < 4; ++r)
            base[16 * m + 4 * g4 + r] = wv[m][r];
    if (lane < 16) {
        float* b2 = ws + ((size_t)pair * 16 + lane) * WSF;
        b2[48] = (float)(esum - eswm);   // exact: |O| << 2^24
        b2[49] = q0v;
    }
}

__global__ __launch_bounds__(256)
void crf_combine(const float* __restrict__ feats,
                 const float* __restrict__ trans,
                 const int* __restrict__ tags,
                 const float* __restrict__ ws,
                 float* __restrict__ out) {
    const int s = blockIdx.x;           // sentence
    const int g = s >> 4;
    const int sidx = s & 15;
    const int tid = threadIdx.x;
    const int lane = tid & 63;
    const int w = tid >> 6;
    const int* tg = tags + (size_t)s * TT;
    const float* fbs = feats + (size_t)s * TT * KK;

    __shared__ float red[4];

    // gold score: 1024 t's over 256 threads (4 waves), LDS reduce
    float gacc = 0.0f;
    #pragma unroll
    for (int it = 0; it < TT / 256; ++it) {
        int t = tid + it * 256;
        int cur = tg[t];
        int prev = (t == 0) ? START_TAG : tg[t - 1];
        gacc += trans[cur * KK + prev] + fbs[(size_t)t * KK + cur];
    }
    #pragma unroll
    for (int off = 32; off; off >>= 1) gacc += __shfl_xor(gacc, off, 64);
    if (lane == 0) red[w] = gacc;
    __syncthreads();

    if (w == 0) {
        // Z tail: sum_i exp(trans[END][i]) * U_last[i]
        float val = 0.0f;
        if (lane < KK)
            val = __expf(trans[END_TAG * KK + lane]) *
                  ws[(((size_t)g * 16 + 15) * 16 + sidx) * WSF + lane];
        #pragma unroll
        for (int off = 32; off; off >>= 1) val += __shfl_xor(val, off, 64);

        // ledgers + scalar stitches (lane-parallel over segments)
        float stv = 0.0f;
        if (lane >= 1 && lane < NSEG) {
            float Uprev0 = ws[(((size_t)g * 16 + lane - 1) * 16 + sidx) * WSF + 0];
            float q0w    = ws[(((size_t)g * 16 + lane) * 16 + sidx) * WSF + 49];
            stv = __logf(Uprev0) - __logf(q0w);
        }
        if (lane < NSEG)
            stv += ws[(((size_t)g * 16 + lane) * 16 + sidx) * WSF + 48] *
                   0.6931471805599453f;
        #pragma unroll
        for (int off = 32; off; off >>= 1) stv += __shfl_xor(stv, off, 64);

        if (lane == 0) {
            float gold = red[0] + red[1] + red[2] + red[3] +
                         trans[END_TAG * KK + tg[TT - 1]];
            out[s] = __logf(val) + stv - gold;
        }
    }
}

extern "C" void kernel_launch(void* const* d_in, const int* in_sizes, int n_in,
                              void* d_out, int out_size, void* d_ws, size_t ws_size,
                              hipStream_t stream) {
    const float* feats = (const float*)d_in[0];
    const float* trans = (const float*)d_in[1];
    const int* tags = (const int*)d_in[2];
    float* out = (float*)d_out;
    float* ws = (float*)d_ws;           // needs NPAIR*16*WSF*4 = 1.64 MB

    crf_seg_kernel<<<NPAIR, 64, 0, stream>>>(feats, trans, ws);
    crf_combine<<<BB, 256, 0, stream>>>(feats, trans, tags, ws, out);
}